// Round 3
// baseline (191.136 us; speedup 1.0000x reference)
//
#include <hip/hip_runtime.h>

#define IMG   512
#define NIMG  48                      // 16 batches * 3 channels
#define NBLK  (NIMG * 64 * 64)        // 196608 8x8 blocks
#define OUTCH ((size_t)NIMG * IMG * IMG) // floats per output tensor: 12582912
#define NTHREADS (NBLK * 8)           // one thread per 8x8-block ROW: 1572864

// Orthonormal 8-point DCT-II matrix: D[k][t]
__device__ constexpr float Dm[8][8] = {
  { 0.3535533905932738f, 0.3535533905932738f, 0.3535533905932738f, 0.3535533905932738f,
    0.3535533905932738f, 0.3535533905932738f, 0.3535533905932738f, 0.3535533905932738f},
  { 0.4903926402016152f, 0.4157348061512726f, 0.2777851165098011f, 0.0975451610080642f,
   -0.0975451610080642f,-0.2777851165098011f,-0.4157348061512726f,-0.4903926402016152f},
  { 0.4619397662556434f, 0.1913417161825449f,-0.1913417161825449f,-0.4619397662556434f,
   -0.4619397662556434f,-0.1913417161825449f, 0.1913417161825449f, 0.4619397662556434f},
  { 0.4157348061512726f,-0.0975451610080642f,-0.4903926402016152f,-0.2777851165098011f,
    0.2777851165098011f, 0.4903926402016152f, 0.0975451610080642f,-0.4157348061512726f},
  { 0.3535533905932738f,-0.3535533905932738f,-0.3535533905932738f, 0.3535533905932738f,
    0.3535533905932738f,-0.3535533905932738f,-0.3535533905932738f, 0.3535533905932738f},
  { 0.2777851165098011f,-0.4903926402016152f, 0.0975451610080642f, 0.4157348061512726f,
   -0.4157348061512726f,-0.0975451610080642f, 0.4903926402016152f,-0.2777851165098011f},
  { 0.1913417161825449f,-0.4619397662556434f, 0.4619397662556434f,-0.1913417161825449f,
   -0.1913417161825449f, 0.4619397662556434f,-0.4619397662556434f, 0.1913417161825449f},
  { 0.0975451610080642f,-0.2777851165098011f, 0.4157348061512726f,-0.4903926402016152f,
    0.4903926402016152f,-0.4157348061512726f, 0.2777851165098011f,-0.0975451610080642f},
};

// Per-column zigzag band bitmasks, byte j = column j, bit k = row k.
// low  = zz in [0,21):  col j -> {0x3F,0x1F,0x0F,0x07,0x03,0x01,0x00,0x00}
// mid  = zz in [21,42): col j -> {0xC0,0xE0,0x70,0x38,0x1C,0x0E,0x07,0x01}
// (verified against the standard 8x8 zigzag; low 21 + mid 21 + high 22 = 64)
#define LO_BITS64  0x00000103070F1F3FULL
#define MID_BITS64 0x01070E1C3870E0C0ULL

__global__ __launch_bounds__(256, 4) void dct_decomp_kernel(
    const float* __restrict__ x, const float* __restrict__ band_scale,
    float* __restrict__ out) {
  // 32 groups per workgroup, 72-float stride (pad 64->72 kills bank conflicts
  // on the scattered transpose writes: 2 lanes/bank = free)
  __shared__ float lds[32 * 72];

  const int tx = threadIdx.x;
  const int r  = tx & 7;                  // row id (load/row-pass), column id (col-pass)
  const int gq = tx >> 3;                 // 8-lane group within workgroup (0..31)
  const int g  = (blockIdx.x << 5) | gq;  // global 8x8-block id (0..196607)

  const int bw  = g & 63;
  const int bh  = (g >> 6) & 63;
  const int img = g >> 12;

  const size_t base = ((size_t)img * IMG + (size_t)bh * 8) * IMG + (size_t)bw * 8;
  const float* src = x + base + (size_t)r * IMG;

  // ---- load my row of the 8x8 block (kept live for the high-band subtraction)
  float xr[8];
  {
    float4 v0 = *(const float4*)(src);
    float4 v1 = *(const float4*)(src + 4);
    xr[0]=v0.x; xr[1]=v0.y; xr[2]=v0.z; xr[3]=v0.w;
    xr[4]=v1.x; xr[5]=v1.y; xr[6]=v1.z; xr[7]=v1.w;
  }

  // ---- row pass: t[l] = (X * D^T)[r][l]
  float t[8];
#pragma unroll
  for (int l = 0; l < 8; ++l) {
    float acc = 0.0f;
#pragma unroll
    for (int n = 0; n < 8; ++n) acc += xr[n] * Dm[l][n];
    t[l] = acc;
  }

  float* L = lds + gq * 72;

  // ---- transpose #1 (within 8-lane group, same wave -> no barrier needed)
  // store column-major: L[l*8 + r] = T[r][l]  =>  L[j*8 + m] = T[m][j]
#pragma unroll
  for (int l = 0; l < 8; ++l) L[l * 8 + r] = t[l];
  float tc[8];
#pragma unroll
  for (int m = 0; m < 8; ++m) tc[m] = L[r * 8 + m];  // I now own column j = r of T

  // ---- col pass: c[k] = (D * T)[k][j] -- column j of the coefficient matrix
  float c[8];
#pragma unroll
  for (int k = 0; k < 8; ++k) {
    float acc = 0.0f;
#pragma unroll
    for (int m = 0; m < 8; ++m) acc += Dm[k][m] * tc[m];
    c[k] = acc;
  }

  const unsigned lo_m  = (unsigned)(LO_BITS64  >> (r * 8)) & 0xFFu;
  const unsigned mid_m = (unsigned)(MID_BITS64 >> (r * 8)) & 0xFFu;

  // masked IDCT of one band; returns my ROW r of the band's spatial image
  auto band_sp = [&](unsigned mbits, float sp[8]) {
    // cm = column j of (C .* mask)
    float cm[8];
#pragma unroll
    for (int k = 0; k < 8; ++k) cm[k] = (mbits & (1u << k)) ? c[k] : 0.0f;
    // u[m] = (D^T * Cm)[m][j]
    float u[8];
#pragma unroll
    for (int m = 0; m < 8; ++m) {
      float acc = 0.0f;
#pragma unroll
      for (int k = 0; k < 8; ++k) acc += Dm[k][m] * cm[k];
      u[m] = acc;
    }
    // transpose: store row-major: L[m*8 + j] = U[m][j]
#pragma unroll
    for (int m = 0; m < 8; ++m) L[m * 8 + r] = u[m];
    float ur[8];
#pragma unroll
    for (int l = 0; l < 8; ++l) ur[l] = L[r * 8 + l];  // row r of U
    // sp[n] = (U * D)[r][n]
#pragma unroll
    for (int n = 0; n < 8; ++n) {
      float acc = 0.0f;
#pragma unroll
      for (int l = 0; l < 8; ++l) acc += ur[l] * Dm[l][n];
      sp[n] = acc;
    }
  };

  float splo[8], spmid[8];
  band_sp(lo_m,  splo);
  band_sp(mid_m, spmid);

  const float s0 = band_scale[0];
  const float s1 = band_scale[1];
  const float s2 = band_scale[2];

  float* dst0 = out + base + (size_t)r * IMG;
  float* dst1 = dst0 + OUTCH;
  float* dst2 = dst1 + OUTCH;

  *(float4*)(dst0)     = make_float4(splo[0]*s0, splo[1]*s0, splo[2]*s0, splo[3]*s0);
  *(float4*)(dst0 + 4) = make_float4(splo[4]*s0, splo[5]*s0, splo[6]*s0, splo[7]*s0);

  *(float4*)(dst1)     = make_float4(spmid[0]*s1, spmid[1]*s1, spmid[2]*s1, spmid[3]*s1);
  *(float4*)(dst1 + 4) = make_float4(spmid[4]*s1, spmid[5]*s1, spmid[6]*s1, spmid[7]*s1);

  // high band is free: masks partition the orthonormal DCT, so lo+mid+high == x
  float h[8];
#pragma unroll
  for (int n = 0; n < 8; ++n) h[n] = (xr[n] - splo[n] - spmid[n]) * s2;
  *(float4*)(dst2)     = make_float4(h[0], h[1], h[2], h[3]);
  *(float4*)(dst2 + 4) = make_float4(h[4], h[5], h[6], h[7]);
}

extern "C" void kernel_launch(void* const* d_in, const int* in_sizes, int n_in,
                              void* d_out, int out_size, void* d_ws, size_t ws_size,
                              hipStream_t stream) {
  const float* x          = (const float*)d_in[0];
  const float* band_scale = (const float*)d_in[1];
  float* out              = (float*)d_out;

  dim3 grid(NTHREADS / 256);  // 6144 workgroups
  dim3 block(256);
  dct_decomp_kernel<<<grid, block, 0, stream>>>(x, band_scale, out);
}